// Round 1
// baseline (216.676 us; speedup 1.0000x reference)
//
#include <hip/hip_runtime.h>

typedef unsigned short u16;
typedef short bfrag __attribute__((ext_vector_type(8)));   // 8 x bf16 (4 VGPRs)
typedef float facc  __attribute__((ext_vector_type(4)));   // 4 x f32 accumulator

__device__ __forceinline__ u16 f2bf(float f){
  union { float f; unsigned u; } v; v.f = f;
  unsigned r = v.u + 0x7fffu + ((v.u >> 16) & 1u);
  return (u16)(r >> 16);
}

__device__ __forceinline__ void gl_lds16(const void* g, void* l){
  __builtin_amdgcn_global_load_lds(
      (const __attribute__((address_space(1))) unsigned int*)g,
      (__attribute__((address_space(3))) unsigned int*)l,
      16, 0, 0);
}

// ---------------- fp32 -> bf16 conversion ----------------
__global__ __launch_bounds__(256) void cvt_kernel(const float* __restrict__ src,
                                                  u16* __restrict__ dst, int n){
  int i = (blockIdx.x * 256 + threadIdx.x) * 4;
  if (i < n){
    float4 f = *(const float4*)(src + i);
    ushort4 o;
    o.x = f2bf(f.x); o.y = f2bf(f.y); o.z = f2bf(f.z); o.w = f2bf(f.w);
    *(ushort4*)(dst + i) = o;
  }
}

// ---------------- bf16 GEMM: C[m,n] = sum_k A[m,k]*B[n,k] + bias[n] ----------------
// EPI==0: write fp32 C row-major.  EPI==1: scatter q/k/v bf16 into [part][B,H,S,64], q scaled by 1/8.
__device__ __forceinline__ void stage_tile(const u16* __restrict__ G, u16* lds,
                                           int row0, int k0, int K, int tid){
  #pragma unroll
  for (int c = 0; c < 2; ++c){
    int e = c * 2048 + tid * 8;
    int row = e >> 5, col = e & 31;
    gl_lds16(G + (size_t)(row0 + row) * K + k0 + col, lds + c * 2048 + (tid >> 6) * 512);
  }
}

template<int EPI>
__global__ __launch_bounds__(256) void gemm_bt(
    const u16* __restrict__ A, const u16* __restrict__ B,
    const float* __restrict__ bias, float* __restrict__ Cf,
    u16* __restrict__ qkv, int M, int N, int K)
{
  __shared__ u16 Ash[2][4096];
  __shared__ u16 Bsh[2][4096];
  const int tid = threadIdx.x, lane = tid & 63;
  const int w = tid >> 6, wm = w >> 1, wn = w & 1;
  const int cl = lane & 15, g8 = (lane >> 4) * 8;
  const int n0 = blockIdx.x * 128, m0 = blockIdx.y * 128;

  facc acc[4][4];
  #pragma unroll
  for (int mi = 0; mi < 4; ++mi)
    #pragma unroll
    for (int ni = 0; ni < 4; ++ni)
      acc[mi][ni] = (facc){0.f, 0.f, 0.f, 0.f};

  const int NT = K >> 5;
  stage_tile(A, Ash[0], m0, 0, K, tid);
  stage_tile(B, Bsh[0], n0, 0, K, tid);
  __syncthreads();
  int cur = 0;
  for (int kt = 0; kt < NT; ++kt){
    if (kt + 1 < NT){
      stage_tile(A, Ash[cur ^ 1], m0, (kt + 1) << 5, K, tid);
      stage_tile(B, Bsh[cur ^ 1], n0, (kt + 1) << 5, K, tid);
    }
    const u16* As = Ash[cur]; const u16* Bs = Bsh[cur];
    bfrag af[4], bfr[4];
    #pragma unroll
    for (int mi = 0; mi < 4; ++mi)
      af[mi] = *(const bfrag*)&As[(wm * 64 + mi * 16 + cl) * 32 + g8];
    #pragma unroll
    for (int ni = 0; ni < 4; ++ni)
      bfr[ni] = *(const bfrag*)&Bs[(wn * 64 + ni * 16 + cl) * 32 + g8];
    #pragma unroll
    for (int mi = 0; mi < 4; ++mi)
      #pragma unroll
      for (int ni = 0; ni < 4; ++ni)
        acc[mi][ni] = __builtin_amdgcn_mfma_f32_16x16x32_bf16(af[mi], bfr[ni], acc[mi][ni], 0, 0, 0);
    __syncthreads();
    cur ^= 1;
  }

  const int r0 = (lane >> 4) * 4;
  #pragma unroll
  for (int mi = 0; mi < 4; ++mi){
    const int mbase = m0 + wm * 64 + mi * 16 + r0;
    #pragma unroll
    for (int ni = 0; ni < 4; ++ni){
      const int n = n0 + wn * 64 + ni * 16 + cl;
      const float bv = bias[n];
      #pragma unroll
      for (int j = 0; j < 4; ++j){
        float v = acc[mi][ni][j] + bv;
        const int mm = mbase + j;
        if (EPI == 0){
          Cf[(size_t)mm * N + n] = v;
        } else {
          const int part = n >> 10, rest = n & 1023;
          const int h = rest >> 6, d = rest & 63;
          const int bb = mm >> 11, s = mm & 2047;
          if (part == 0) v *= 0.125f;   // fold 1/sqrt(dh)=1/8 into q (exact in fp)
          qkv[(size_t)part * 4194304 + (size_t)((bb * 16 + h) * 2048 + s) * 64 + d] = f2bf(v);
        }
      }
    }
  }
}

// ---------------- swapped-role causal flash attention ----------------
// out[i] = sum_{j<=i} softmax_j( Kproj[i] . Qproj[j]/8 ) * V[j]
// Qf = k-projection (output rows), Kf = q-projection (pre-scaled), Vf = v.
__global__ __launch_bounds__(256) void attn_kernel(
    const u16* __restrict__ qarr, const u16* __restrict__ karr,
    const u16* __restrict__ varr, u16* __restrict__ aout,
    const int* __restrict__ cmask)
{
  __shared__ u16 q_lds[128 * 72];
  __shared__ u16 k_lds[64 * 72];
  __shared__ u16 v_lds[64 * 72];
  const int tid = threadIdx.x, lane = tid & 63, w = tid >> 6;
  const int cl = lane & 15, g8 = (lane >> 4) * 8, r0 = (lane >> 4) * 4;
  const int bi = blockIdx.x, bh = blockIdx.y;
  const int i0 = bi * 128;
  const u16* Qh = karr + (size_t)bh * 131072;  // role swap: output rows come from k-proj
  const u16* Kh = qarr + (size_t)bh * 131072;  // keys are q-proj (already /8)
  const u16* Vh = varr + (size_t)bh * 131072;
  const bool do_mask = (cmask[0] != 0);

  // stage Qf tile [128][64] -> LDS stride 72
  #pragma unroll
  for (int r = 0; r < 4; ++r){
    int e = (r * 256 + tid) * 8;
    int row = e >> 6, col = e & 63;
    uint4 val = *(const uint4*)(Qh + (size_t)(i0 + row) * 64 + col);
    *(uint4*)&q_lds[row * 72 + col] = val;
  }
  __syncthreads();
  bfrag aq[2][2];
  #pragma unroll
  for (int rf = 0; rf < 2; ++rf)
    #pragma unroll
    for (int kk = 0; kk < 2; ++kk)
      aq[rf][kk] = *(const bfrag*)&q_lds[(w * 32 + rf * 16 + cl) * 72 + kk * 32 + g8];

  float m_s[2][4], l_s[2][4];
  facc o_acc[2][4];
  #pragma unroll
  for (int rf = 0; rf < 2; ++rf){
    #pragma unroll
    for (int j = 0; j < 4; ++j){ m_s[rf][j] = -1e30f; l_s[rf][j] = 0.f; }
    #pragma unroll
    for (int df = 0; df < 4; ++df) o_acc[rf][df] = (facc){0.f, 0.f, 0.f, 0.f};
  }
  u16* p_lds = q_lds + w * 32 * 72;   // reuse retired Q region, wave-private 32 rows

  const int njt = do_mask ? (2 * bi + 2) : 32;
  for (int jt = 0; jt < njt; ++jt){
    __syncthreads();
    // stage Kf tile [64][64]
    #pragma unroll
    for (int r = 0; r < 2; ++r){
      int e = (r * 256 + tid) * 8;
      int row = e >> 6, col = e & 63;
      uint4 val = *(const uint4*)(Kh + (size_t)(jt * 64 + row) * 64 + col);
      *(uint4*)&k_lds[row * 72 + col] = val;
    }
    // stage V transposed: v_lds[d][j]
    #pragma unroll
    for (int r = 0; r < 2; ++r){
      int jrow = r * 32 + (tid >> 3), d0 = (tid & 7) * 8;
      uint4 val = *(const uint4*)(Vh + (size_t)(jt * 64 + jrow) * 64 + d0);
      const u16* pv = (const u16*)&val;
      #pragma unroll
      for (int e2 = 0; e2 < 8; ++e2) v_lds[(d0 + e2) * 72 + jrow] = pv[e2];
    }
    __syncthreads();

    // S = Qf . Kf^T   (wave: 32 rows x 64 cols)
    facc sacc[2][4];
    #pragma unroll
    for (int rf = 0; rf < 2; ++rf)
      #pragma unroll
      for (int cf = 0; cf < 4; ++cf)
        sacc[rf][cf] = (facc){0.f, 0.f, 0.f, 0.f};
    #pragma unroll
    for (int kk = 0; kk < 2; ++kk){
      #pragma unroll
      for (int cf = 0; cf < 4; ++cf){
        bfrag bk = *(const bfrag*)&k_lds[(cf * 16 + cl) * 72 + kk * 32 + g8];
        #pragma unroll
        for (int rf = 0; rf < 2; ++rf)
          sacc[rf][cf] = __builtin_amdgcn_mfma_f32_16x16x32_bf16(aq[rf][kk], bk, sacc[rf][cf], 0, 0, 0);
      }
    }
    if (do_mask && (jt * 64 + 63 > i0 + w * 32)){
      #pragma unroll
      for (int rf = 0; rf < 2; ++rf)
        #pragma unroll
        for (int cf = 0; cf < 4; ++cf)
          #pragma unroll
          for (int j = 0; j < 4; ++j){
            int irow = i0 + w * 32 + rf * 16 + r0 + j;
            int jcol = jt * 64 + cf * 16 + cl;
            if (jcol > irow) sacc[rf][cf][j] = -1e30f;
          }
    }
    // online softmax (row reduce over 16 lanes)
    #pragma unroll
    for (int rf = 0; rf < 2; ++rf){
      float tmax[4], scale[4], rsum[4];
      #pragma unroll
      for (int j = 0; j < 4; ++j)
        tmax[j] = fmaxf(fmaxf(sacc[rf][0][j], sacc[rf][1][j]),
                        fmaxf(sacc[rf][2][j], sacc[rf][3][j]));
      #pragma unroll
      for (int off = 8; off >= 1; off >>= 1)
        #pragma unroll
        for (int j = 0; j < 4; ++j)
          tmax[j] = fmaxf(tmax[j], __shfl_xor(tmax[j], off));
      #pragma unroll
      for (int j = 0; j < 4; ++j){
        float mn = fmaxf(m_s[rf][j], tmax[j]);
        scale[j] = __expf(m_s[rf][j] - mn);
        m_s[rf][j] = mn;
        rsum[j] = 0.f;
      }
      #pragma unroll
      for (int cf = 0; cf < 4; ++cf)
        #pragma unroll
        for (int j = 0; j < 4; ++j){
          float p = __expf(sacc[rf][cf][j] - m_s[rf][j]);
          sacc[rf][cf][j] = p;
          rsum[j] += p;
        }
      #pragma unroll
      for (int off = 8; off >= 1; off >>= 1)
        #pragma unroll
        for (int j = 0; j < 4; ++j)
          rsum[j] += __shfl_xor(rsum[j], off);
      #pragma unroll
      for (int j = 0; j < 4; ++j)
        l_s[rf][j] = l_s[rf][j] * scale[j] + rsum[j];
      #pragma unroll
      for (int df = 0; df < 4; ++df)
        #pragma unroll
        for (int j = 0; j < 4; ++j)
          o_acc[rf][df][j] *= scale[j];
      #pragma unroll
      for (int cf = 0; cf < 4; ++cf)
        #pragma unroll
        for (int j = 0; j < 4; ++j)
          p_lds[(rf * 16 + r0 + j) * 72 + cf * 16 + cl] = f2bf(sacc[rf][cf][j]);
    }
    // O += P . V   (A = P rows, B = Vt rows = V columns)
    #pragma unroll
    for (int kk = 0; kk < 2; ++kk){
      bfrag ap[2];
      #pragma unroll
      for (int rf = 0; rf < 2; ++rf)
        ap[rf] = *(const bfrag*)&p_lds[(rf * 16 + cl) * 72 + kk * 32 + g8];
      #pragma unroll
      for (int df = 0; df < 4; ++df){
        bfrag bv = *(const bfrag*)&v_lds[(df * 16 + cl) * 72 + kk * 32 + g8];
        #pragma unroll
        for (int rf = 0; rf < 2; ++rf)
          o_acc[rf][df] = __builtin_amdgcn_mfma_f32_16x16x32_bf16(ap[rf], bv, o_acc[rf][df], 0, 0, 0);
      }
    }
  }
  // epilogue: divide by l, write [B,S,D] bf16 for the output projection
  const int bb = bh >> 4, h = bh & 15;
  #pragma unroll
  for (int rf = 0; rf < 2; ++rf)
    #pragma unroll
    for (int df = 0; df < 4; ++df)
      #pragma unroll
      for (int j = 0; j < 4; ++j){
        int row = i0 + w * 32 + rf * 16 + r0 + j;
        int col = h * 64 + df * 16 + cl;
        float v = o_acc[rf][df][j] / l_s[rf][j];
        aout[(size_t)(bb * 2048 + row) * 1024 + col] = f2bf(v);
      }
}

// ---------------- launch ----------------
extern "C" void kernel_launch(void* const* d_in, const int* in_sizes, int n_in,
                              void* d_out, int out_size, void* d_ws, size_t ws_size,
                              hipStream_t stream)
{
  const float* x     = (const float*)d_in[0];
  const float* w_in  = (const float*)d_in[1];
  const float* b_in  = (const float*)d_in[2];
  const float* w_out = (const float*)d_in[3];
  const float* b_out = (const float*)d_in[4];
  const int*   cmask = (const int*)d_in[5];

  u16* ws     = (u16*)d_ws;
  u16* xb     = ws;                 // 4096x1024
  u16* winb   = ws + 4194304;       // 3072x1024
  u16* woutb  = ws + 7340032;       // 1024x1024
  u16* qs     = ws + 8388608;       // q,k,v: 3 x [2,16,2048,64]
  u16* attn_o = ws + 20971520;      // 4096x1024

  cvt_kernel<<<4096, 256, 0, stream>>>(x, xb, 4194304);
  cvt_kernel<<<3072, 256, 0, stream>>>(w_in, winb, 3145728);
  cvt_kernel<<<1024, 256, 0, stream>>>(w_out, woutb, 1048576);

  gemm_bt<1><<<dim3(24, 32), 256, 0, stream>>>(xb, winb, b_in, nullptr, qs, 4096, 3072, 1024);

  attn_kernel<<<dim3(16, 32), 256, 0, stream>>>(qs, qs + 4194304, qs + 8388608, attn_o, cmask);

  gemm_bt<0><<<dim3(8, 32), 256, 0, stream>>>(attn_o, woutb, b_out, (float*)d_out, nullptr,
                                              4096, 1024, 1024);
}

// Round 2
// 189.745 us; speedup vs baseline: 1.1419x; 1.1419x over previous
//
#include <hip/hip_runtime.h>

typedef unsigned short u16;
typedef short bfrag __attribute__((ext_vector_type(8)));   // 8 x bf16 (4 VGPRs)
typedef float facc  __attribute__((ext_vector_type(4)));   // 4 x f32 accumulator

__device__ __forceinline__ u16 f2bf(float f){
  union { float f; unsigned u; } v; v.f = f;
  unsigned r = v.u + 0x7fffu + ((v.u >> 16) & 1u);
  return (u16)(r >> 16);
}

__device__ __forceinline__ void gl_lds16(const void* g, void* l){
  __builtin_amdgcn_global_load_lds(
      (const __attribute__((address_space(1))) unsigned int*)g,
      (__attribute__((address_space(3))) unsigned int*)l,
      16, 0, 0);
}

// ---------------- fp32 -> bf16 conversion ----------------
__global__ __launch_bounds__(256) void cvt_kernel(const float* __restrict__ src,
                                                  u16* __restrict__ dst, int n){
  int i = (blockIdx.x * 256 + threadIdx.x) * 4;
  if (i < n){
    float4 f = *(const float4*)(src + i);
    ushort4 o;
    o.x = f2bf(f.x); o.y = f2bf(f.y); o.z = f2bf(f.z); o.w = f2bf(f.w);
    *(ushort4*)(dst + i) = o;
  }
}

// ---------------- bf16 GEMM: C[m,n] = sum_k A[m,k]*B[n,k] + bias[n] ----------------
__device__ __forceinline__ void stage_tile(const u16* __restrict__ G, u16* lds,
                                           int row0, int k0, int K, int tid){
  #pragma unroll
  for (int c = 0; c < 2; ++c){
    int e = c * 2048 + tid * 8;
    int row = e >> 5, col = e & 31;
    gl_lds16(G + (size_t)(row0 + row) * K + k0 + col, lds + c * 2048 + (tid >> 6) * 512);
  }
}

template<int EPI>
__global__ __launch_bounds__(256) void gemm_bt(
    const u16* __restrict__ A, const u16* __restrict__ B,
    const float* __restrict__ bias, float* __restrict__ Cf,
    u16* __restrict__ qkv, int M, int N, int K)
{
  __shared__ u16 Ash[2][4096];
  __shared__ u16 Bsh[2][4096];
  const int tid = threadIdx.x, lane = tid & 63;
  const int w = tid >> 6, wm = w >> 1, wn = w & 1;
  const int cl = lane & 15, g8 = (lane >> 4) * 8;
  const int n0 = blockIdx.x * 128, m0 = blockIdx.y * 128;

  facc acc[4][4];
  #pragma unroll
  for (int mi = 0; mi < 4; ++mi)
    #pragma unroll
    for (int ni = 0; ni < 4; ++ni)
      acc[mi][ni] = (facc){0.f, 0.f, 0.f, 0.f};

  const int NT = K >> 5;
  stage_tile(A, Ash[0], m0, 0, K, tid);
  stage_tile(B, Bsh[0], n0, 0, K, tid);
  __syncthreads();
  int cur = 0;
  for (int kt = 0; kt < NT; ++kt){
    if (kt + 1 < NT){
      stage_tile(A, Ash[cur ^ 1], m0, (kt + 1) << 5, K, tid);
      stage_tile(B, Bsh[cur ^ 1], n0, (kt + 1) << 5, K, tid);
    }
    const u16* As = Ash[cur]; const u16* Bs = Bsh[cur];
    bfrag af[4], bfr[4];
    #pragma unroll
    for (int mi = 0; mi < 4; ++mi)
      af[mi] = *(const bfrag*)&As[(wm * 64 + mi * 16 + cl) * 32 + g8];
    #pragma unroll
    for (int ni = 0; ni < 4; ++ni)
      bfr[ni] = *(const bfrag*)&Bs[(wn * 64 + ni * 16 + cl) * 32 + g8];
    #pragma unroll
    for (int mi = 0; mi < 4; ++mi)
      #pragma unroll
      for (int ni = 0; ni < 4; ++ni)
        acc[mi][ni] = __builtin_amdgcn_mfma_f32_16x16x32_bf16(af[mi], bfr[ni], acc[mi][ni], 0, 0, 0);
    __syncthreads();
    cur ^= 1;
  }

  const int r0 = (lane >> 4) * 4;
  #pragma unroll
  for (int mi = 0; mi < 4; ++mi){
    const int mbase = m0 + wm * 64 + mi * 16 + r0;
    #pragma unroll
    for (int ni = 0; ni < 4; ++ni){
      const int n = n0 + wn * 64 + ni * 16 + cl;
      const float bv = bias[n];
      #pragma unroll
      for (int j = 0; j < 4; ++j){
        float v = acc[mi][ni][j] + bv;
        const int mm = mbase + j;
        if (EPI == 0){
          Cf[(size_t)mm * N + n] = v;
        } else {
          const int part = n >> 10, rest = n & 1023;
          const int h = rest >> 6, d = rest & 63;
          const int bb = mm >> 11, s = mm & 2047;
          // fold 1/sqrt(dh)=1/8 AND log2(e) into q so attention uses exp2 directly
          if (part == 0) v *= 0.18033688011112042f;
          qkv[(size_t)part * 4194304 + (size_t)((bb * 16 + h) * 2048 + s) * 64 + d] = f2bf(v);
        }
      }
    }
  }
}

// ---------------- swapped-role causal flash attention ----------------
// out[i] = sum_{j<=i} softmax_j( Kproj[i] . Qproj[j]*log2e/8 ) * V[j], exp2 domain.
#define LQ 72

__global__ __launch_bounds__(256) void attn_kernel(
    const u16* __restrict__ qarr, const u16* __restrict__ karr,
    const u16* __restrict__ varr, u16* __restrict__ aout,
    const int* __restrict__ cmask)
{
  __shared__ u16 k_lds[64 * LQ];
  __shared__ u16 v_lds[64 * LQ];
  __shared__ u16 p_buf[64 * LQ];
  const int tid = threadIdx.x, lane = tid & 63, w = tid >> 6;
  const int cl = lane & 15, g8 = (lane >> 4) * 8, r0 = (lane >> 4) * 4;
  const int bh = blockIdx.x;                    // bh -> XCD (K/V L2 locality)
  const int bi = 31 - (int)blockIdx.y;          // heavy tiles dispatch first
  const int i0 = bi * 64;
  const u16* Qh = karr + (size_t)bh * 131072;   // output rows come from k-proj
  const u16* Kh = qarr + (size_t)bh * 131072;   // keys are q-proj (pre-scaled)
  const u16* Vh = varr + (size_t)bh * 131072;
  const bool do_mask = (cmask[0] != 0);

  // Q fragments straight from global (one 16B load per kk, per-wave rows)
  bfrag aq[2];
  #pragma unroll
  for (int kk = 0; kk < 2; ++kk)
    aq[kk] = *(const bfrag*)(Qh + (size_t)(i0 + w * 16 + cl) * 64 + kk * 32 + g8);

  float m_s[4], l_s[4];
  facc o_acc[4];
  #pragma unroll
  for (int j = 0; j < 4; ++j){ m_s[j] = -1e30f; l_s[j] = 0.f; }
  #pragma unroll
  for (int df = 0; df < 4; ++df) o_acc[df] = (facc){0.f, 0.f, 0.f, 0.f};

  u16* p_lds = p_buf + w * 16 * LQ;             // wave-private P tile
  const int c8 = tid & 7;
  const int njt = do_mask ? (bi + 1) : 32;

  for (int jt = 0; jt < njt; ++jt){
    __syncthreads();
    // stage K tile [64 rows][64 feat], padded stride
    #pragma unroll
    for (int r = 0; r < 2; ++r){
      int e = (r * 256 + tid) * 8;
      int row = e >> 6, col = e & 63;
      *(uint4*)&k_lds[row * LQ + col] =
          *(const uint4*)(Kh + (size_t)(jt * 64 + row) * 64 + col);
    }
    // stage V transposed [d][j]; rotated write order -> conflict-free banks
    #pragma unroll
    for (int r = 0; r < 2; ++r){
      int jrow = r * 32 + (tid >> 3);
      uint4 val = *(const uint4*)(Vh + (size_t)(jt * 64 + jrow) * 64 + c8 * 8);
      const u16* pv = (const u16*)&val;
      #pragma unroll
      for (int e2 = 0; e2 < 8; ++e2){
        int idx = (e2 + c8) & 7;
        v_lds[(c8 * 8 + idx) * LQ + jrow] = pv[idx];
      }
    }
    __syncthreads();

    // S = Qf . Kf^T  (wave: 16 rows x 64 cols)
    facc sacc[4];
    #pragma unroll
    for (int cf = 0; cf < 4; ++cf) sacc[cf] = (facc){0.f, 0.f, 0.f, 0.f};
    __builtin_amdgcn_s_setprio(1);
    #pragma unroll
    for (int kk = 0; kk < 2; ++kk)
      #pragma unroll
      for (int cf = 0; cf < 4; ++cf){
        bfrag bk = *(const bfrag*)&k_lds[(cf * 16 + cl) * LQ + kk * 32 + g8];
        sacc[cf] = __builtin_amdgcn_mfma_f32_16x16x32_bf16(aq[kk], bk, sacc[cf], 0, 0, 0);
      }
    __builtin_amdgcn_s_setprio(0);

    if (do_mask && jt == bi){                   // only the diagonal tile masks
      #pragma unroll
      for (int cf = 0; cf < 4; ++cf)
        #pragma unroll
        for (int j = 0; j < 4; ++j)
          if (cf * 16 + cl > w * 16 + r0 + j) sacc[cf][j] = -1e30f;
    }

    // online softmax, exp2 domain, defer-max THR=8
    float tmax[4];
    #pragma unroll
    for (int j = 0; j < 4; ++j)
      tmax[j] = fmaxf(fmaxf(sacc[0][j], sacc[1][j]), fmaxf(sacc[2][j], sacc[3][j]));
    #pragma unroll
    for (int off = 8; off >= 1; off >>= 1)
      #pragma unroll
      for (int j = 0; j < 4; ++j)
        tmax[j] = fmaxf(tmax[j], __shfl_xor(tmax[j], off));
    float dm = tmax[0] - m_s[0];
    #pragma unroll
    for (int j = 1; j < 4; ++j) dm = fmaxf(dm, tmax[j] - m_s[j]);
    if (__any(dm > 8.0f)){
      #pragma unroll
      for (int j = 0; j < 4; ++j){
        float nm = fmaxf(m_s[j], tmax[j]);
        float sc = __builtin_amdgcn_exp2f(m_s[j] - nm);
        m_s[j] = nm;
        l_s[j] *= sc;
        #pragma unroll
        for (int df = 0; df < 4; ++df) o_acc[df][j] *= sc;
      }
    }
    float rsum[4] = {0.f, 0.f, 0.f, 0.f};
    #pragma unroll
    for (int cf = 0; cf < 4; ++cf)
      #pragma unroll
      for (int j = 0; j < 4; ++j){
        float p = __builtin_amdgcn_exp2f(sacc[cf][j] - m_s[j]);
        unsigned pb = __float_as_uint(p);
        p_lds[(r0 + j) * LQ + cf * 16 + cl] = (u16)(pb >> 16);      // trunc bf16
        rsum[j] += __uint_as_float(pb & 0xffff0000u);               // sum what we stored
      }
    #pragma unroll
    for (int off = 8; off >= 1; off >>= 1)
      #pragma unroll
      for (int j = 0; j < 4; ++j)
        rsum[j] += __shfl_xor(rsum[j], off);
    #pragma unroll
    for (int j = 0; j < 4; ++j) l_s[j] += rsum[j];

    // O += P . V  (B operand from transposed-V tile)
    __builtin_amdgcn_s_setprio(1);
    #pragma unroll
    for (int kk = 0; kk < 2; ++kk){
      bfrag ap = *(const bfrag*)&p_lds[cl * LQ + kk * 32 + g8];
      #pragma unroll
      for (int df = 0; df < 4; ++df){
        bfrag bv = *(const bfrag*)&v_lds[(df * 16 + cl) * LQ + kk * 32 + g8];
        o_acc[df] = __builtin_amdgcn_mfma_f32_16x16x32_bf16(ap, bv, o_acc[df], 0, 0, 0);
      }
    }
    __builtin_amdgcn_s_setprio(0);
  }

  // epilogue
  const int bb = bh >> 4, h = bh & 15;
  float inv[4];
  #pragma unroll
  for (int j = 0; j < 4; ++j) inv[j] = 1.0f / l_s[j];
  #pragma unroll
  for (int df = 0; df < 4; ++df)
    #pragma unroll
    for (int j = 0; j < 4; ++j){
      int row = i0 + w * 16 + r0 + j;
      int col = h * 64 + df * 16 + cl;
      aout[(size_t)(bb * 2048 + row) * 1024 + col] = f2bf(o_acc[df][j] * inv[j]);
    }
}

// ---------------- launch ----------------
extern "C" void kernel_launch(void* const* d_in, const int* in_sizes, int n_in,
                              void* d_out, int out_size, void* d_ws, size_t ws_size,
                              hipStream_t stream)
{
  const float* x     = (const float*)d_in[0];
  const float* w_in  = (const float*)d_in[1];
  const float* b_in  = (const float*)d_in[2];
  const float* w_out = (const float*)d_in[3];
  const float* b_out = (const float*)d_in[4];
  const int*   cmask = (const int*)d_in[5];

  u16* ws     = (u16*)d_ws;
  u16* xb     = ws;                 // 4096x1024
  u16* winb   = ws + 4194304;       // 3072x1024
  u16* woutb  = ws + 7340032;       // 1024x1024
  u16* qs     = ws + 8388608;       // q,k,v: 3 x [2,16,2048,64]
  u16* attn_o = ws + 20971520;      // 4096x1024

  cvt_kernel<<<4096, 256, 0, stream>>>(x, xb, 4194304);
  cvt_kernel<<<3072, 256, 0, stream>>>(w_in, winb, 3145728);
  cvt_kernel<<<1024, 256, 0, stream>>>(w_out, woutb, 1048576);

  gemm_bt<1><<<dim3(24, 32), 256, 0, stream>>>(xb, winb, b_in, nullptr, qs, 4096, 3072, 1024);

  attn_kernel<<<dim3(32, 32), 256, 0, stream>>>(qs, qs + 4194304, qs + 8388608, attn_o, cmask);

  gemm_bt<0><<<dim3(8, 32), 256, 0, stream>>>(attn_o, woutb, b_out, (float*)d_out, nullptr,
                                              4096, 1024, 1024);
}

// Round 3
// 171.222 us; speedup vs baseline: 1.2655x; 1.1082x over previous
//
#include <hip/hip_runtime.h>

typedef unsigned short u16;
typedef short bfrag __attribute__((ext_vector_type(8)));   // 8 x bf16 (4 VGPRs)
typedef float facc  __attribute__((ext_vector_type(4)));   // 4 x f32 accumulator

__device__ __forceinline__ u16 f2bf(float f){
  union { float f; unsigned u; } v; v.f = f;
  unsigned r = v.u + 0x7fffu + ((v.u >> 16) & 1u);
  return (u16)(r >> 16);
}

__device__ __forceinline__ void gl_lds16(const void* g, void* l){
  __builtin_amdgcn_global_load_lds(
      (const __attribute__((address_space(1))) unsigned int*)g,
      (__attribute__((address_space(3))) unsigned int*)l,
      16, 0, 0);
}

// ---------------- fp32 -> bf16 conversion ----------------
__global__ __launch_bounds__(256) void cvt_kernel(const float* __restrict__ src,
                                                  u16* __restrict__ dst, int n){
  int i = (blockIdx.x * 256 + threadIdx.x) * 4;
  if (i < n){
    float4 f = *(const float4*)(src + i);
    ushort4 o;
    o.x = f2bf(f.x); o.y = f2bf(f.y); o.z = f2bf(f.z); o.w = f2bf(f.w);
    *(ushort4*)(dst + i) = o;
  }
}

// ---------------- bf16 GEMM: C[m,n] = sum_k A[m,k]*B[n,k] + bias[n] ----------------
__device__ __forceinline__ void stage_tile(const u16* __restrict__ G, u16* lds,
                                           int row0, int k0, int K, int tid){
  #pragma unroll
  for (int c = 0; c < 2; ++c){
    int e = c * 2048 + tid * 8;
    int row = e >> 5, col = e & 31;
    gl_lds16(G + (size_t)(row0 + row) * K + k0 + col, lds + c * 2048 + (tid >> 6) * 512);
  }
}

template<int EPI>
__global__ __launch_bounds__(256) void gemm_bt(
    const u16* __restrict__ A, const u16* __restrict__ B,
    const float* __restrict__ bias, float* __restrict__ Cf,
    u16* __restrict__ qkv, int M, int N, int K)
{
  __shared__ u16 Ash[2][4096];
  __shared__ u16 Bsh[2][4096];
  const int tid = threadIdx.x, lane = tid & 63;
  const int w = tid >> 6, wm = w >> 1, wn = w & 1;
  const int cl = lane & 15, g8 = (lane >> 4) * 8;
  const int n0 = blockIdx.x * 128, m0 = blockIdx.y * 128;

  facc acc[4][4];
  #pragma unroll
  for (int mi = 0; mi < 4; ++mi)
    #pragma unroll
    for (int ni = 0; ni < 4; ++ni)
      acc[mi][ni] = (facc){0.f, 0.f, 0.f, 0.f};

  const int NT = K >> 5;
  stage_tile(A, Ash[0], m0, 0, K, tid);
  stage_tile(B, Bsh[0], n0, 0, K, tid);
  __syncthreads();
  int cur = 0;
  for (int kt = 0; kt < NT; ++kt){
    if (kt + 1 < NT){
      stage_tile(A, Ash[cur ^ 1], m0, (kt + 1) << 5, K, tid);
      stage_tile(B, Bsh[cur ^ 1], n0, (kt + 1) << 5, K, tid);
    }
    const u16* As = Ash[cur]; const u16* Bs = Bsh[cur];
    bfrag af[4], bfr[4];
    #pragma unroll
    for (int mi = 0; mi < 4; ++mi)
      af[mi] = *(const bfrag*)&As[(wm * 64 + mi * 16 + cl) * 32 + g8];
    #pragma unroll
    for (int ni = 0; ni < 4; ++ni)
      bfr[ni] = *(const bfrag*)&Bs[(wn * 64 + ni * 16 + cl) * 32 + g8];
    #pragma unroll
    for (int mi = 0; mi < 4; ++mi)
      #pragma unroll
      for (int ni = 0; ni < 4; ++ni)
        acc[mi][ni] = __builtin_amdgcn_mfma_f32_16x16x32_bf16(af[mi], bfr[ni], acc[mi][ni], 0, 0, 0);
    __syncthreads();
    cur ^= 1;
  }

  const int r0 = (lane >> 4) * 4;
  #pragma unroll
  for (int mi = 0; mi < 4; ++mi){
    const int mbase = m0 + wm * 64 + mi * 16 + r0;
    #pragma unroll
    for (int ni = 0; ni < 4; ++ni){
      const int n = n0 + wn * 64 + ni * 16 + cl;
      const float bv = bias[n];
      #pragma unroll
      for (int j = 0; j < 4; ++j){
        float v = acc[mi][ni][j] + bv;
        const int mm = mbase + j;
        if (EPI == 0){
          Cf[(size_t)mm * N + n] = v;
        } else {
          const int part = n >> 10, rest = n & 1023;
          const int h = rest >> 6, d = rest & 63;
          const int bb = mm >> 11, s = mm & 2047;
          // fold 1/sqrt(dh)=1/8 AND log2(e) into q so attention uses exp2 directly
          if (part == 0) v *= 0.18033688011112042f;
          qkv[(size_t)part * 4194304 + (size_t)((bb * 16 + h) * 2048 + s) * 64 + d] = f2bf(v);
        }
      }
    }
  }
}

// ---------------- swapped-role causal flash attention ----------------
// out[i] = sum_{j<=i} softmax_j( Kproj[i] . Qproj[j]*log2e/8 ) * V[j], exp2 domain.
// Computes S^T = mfma(K_rows, Q_rows) so each lane owns one q-row's P slice.
#define KS 72   // K/V LDS row stride (u16)
#define PS 72   // P LDS row stride (u16), 144B -> 16B-aligned b128 reads

__global__ __launch_bounds__(256) void attn_kernel(
    const u16* __restrict__ qarr, const u16* __restrict__ karr,
    const u16* __restrict__ varr, u16* __restrict__ aout,
    const int* __restrict__ cmask)
{
  __shared__ u16 k_lds[2][64 * KS];
  __shared__ u16 v_lds[2][64 * KS];   // transposed: [d][j]
  __shared__ u16 p_all[4][16 * PS];   // per-wave P tile [i][j]
  const int tid = threadIdx.x, lane = tid & 63, w = tid >> 6;
  const int cl = lane & 15, g = lane >> 4, g8 = g * 8;
  const int bh = blockIdx.x;                    // bh -> XCD (K/V L2 locality)
  const int bi = 31 - (int)blockIdx.y;          // heavy tiles dispatch first
  const int i0 = bi * 64;
  const u16* Qh = karr + (size_t)bh * 131072;   // output rows come from k-proj
  const u16* Kh = qarr + (size_t)bh * 131072;   // keys are q-proj (pre-scaled)
  const u16* Vh = varr + (size_t)bh * 131072;
  const bool do_mask = (cmask[0] != 0);

  // Q as B-operand fragments, straight from global
  bfrag bq[2];
  #pragma unroll
  for (int kk = 0; kk < 2; ++kk)
    bq[kk] = *(const bfrag*)(Qh + (size_t)(i0 + w * 16 + cl) * 64 + kk * 32 + g8);

  float m_s = -1e30f, l_s = 0.f;
  facc o_acc[4];
  #pragma unroll
  for (int df = 0; df < 4; ++df) o_acc[df] = (facc){0.f, 0.f, 0.f, 0.f};

  u16* pl = &p_all[w][0];
  const int c8 = tid & 7;
  const int krow = tid >> 3, kcol = c8 * 8;     // staging coords (2 passes of 32 rows)
  const int njt = do_mask ? (bi + 1) : 32;

  uint4 ka[2], va[2];
  // prologue: stage tile 0
  #pragma unroll
  for (int r = 0; r < 2; ++r){
    ka[r] = *(const uint4*)(Kh + (size_t)(r * 32 + krow) * 64 + kcol);
    va[r] = *(const uint4*)(Vh + (size_t)(r * 32 + krow) * 64 + kcol);
  }
  #pragma unroll
  for (int r = 0; r < 2; ++r)
    *(uint4*)&k_lds[0][(r * 32 + krow) * KS + kcol] = ka[r];
  #pragma unroll
  for (int r = 0; r < 2; ++r){
    const u16* pv = (const u16*)&va[r];
    #pragma unroll
    for (int e2 = 0; e2 < 8; ++e2){
      int idx = (e2 + c8) & 7;                  // rotated order: conflict-reduced
      v_lds[0][(kcol + idx) * KS + r * 32 + krow] = pv[idx];
    }
  }
  __syncthreads();

  int cur = 0;
  for (int jt = 0; jt < njt; ++jt){
    const bool more = (jt + 1 < njt);
    if (more){                                  // prefetch next tile into regs (T14)
      #pragma unroll
      for (int r = 0; r < 2; ++r){
        ka[r] = *(const uint4*)(Kh + (size_t)((jt + 1) * 64 + r * 32 + krow) * 64 + kcol);
        va[r] = *(const uint4*)(Vh + (size_t)((jt + 1) * 64 + r * 32 + krow) * 64 + kcol);
      }
    }
    const u16* kc = k_lds[cur];
    const u16* vc = v_lds[cur];

    // S^T = K . Q^T : C[row=j_loc][col=i_loc]; lane: i=cl, j = 16cf+4g+reg
    facc s[4];
    #pragma unroll
    for (int cf = 0; cf < 4; ++cf) s[cf] = (facc){0.f, 0.f, 0.f, 0.f};
    __builtin_amdgcn_s_setprio(1);
    #pragma unroll
    for (int kk = 0; kk < 2; ++kk)
      #pragma unroll
      for (int cf = 0; cf < 4; ++cf){
        bfrag ak = *(const bfrag*)&kc[(cf * 16 + cl) * KS + kk * 32 + g8];
        s[cf] = __builtin_amdgcn_mfma_f32_16x16x32_bf16(ak, bq[kk], s[cf], 0, 0, 0);
      }
    __builtin_amdgcn_s_setprio(0);

    if (do_mask && jt == bi){                   // diagonal tile: mask j_loc > i_loc
      #pragma unroll
      for (int cf = 0; cf < 4; ++cf)
        #pragma unroll
        for (int r = 0; r < 4; ++r)
          if (cf * 16 + 4 * g + r > w * 16 + cl) s[cf][r] = -1e30f;
    }

    // per-lane row softmax over 16 j's + 2 shfls across groups
    float tmax = fmaxf(fmaxf(fmaxf(s[0][0], s[0][1]), fmaxf(s[0][2], s[0][3])),
                       fmaxf(fmaxf(s[1][0], s[1][1]), fmaxf(s[1][2], s[1][3])));
    tmax = fmaxf(tmax, fmaxf(fmaxf(fmaxf(s[2][0], s[2][1]), fmaxf(s[2][2], s[2][3])),
                             fmaxf(fmaxf(s[3][0], s[3][1]), fmaxf(s[3][2], s[3][3]))));
    tmax = fmaxf(tmax, __shfl_xor(tmax, 16));
    tmax = fmaxf(tmax, __shfl_xor(tmax, 32));
    if (__any(tmax - m_s > 8.0f)){              // defer-max (THR=8)
      float nm = fmaxf(m_s, tmax);
      float sc = __builtin_amdgcn_exp2f(m_s - nm);
      m_s = nm; l_s *= sc;
      float scr[4];
      #pragma unroll
      for (int r = 0; r < 4; ++r) scr[r] = __shfl(sc, g * 20 + r);  // lane 16g + (4g+r)
      #pragma unroll
      for (int df = 0; df < 4; ++df)
        #pragma unroll
        for (int r = 0; r < 4; ++r) o_acc[df][r] *= scr[r];
    }
    float rsum = 0.f;
    unsigned pk[4][2];
    #pragma unroll
    for (int cf = 0; cf < 4; ++cf)
      #pragma unroll
      for (int h2 = 0; h2 < 2; ++h2){
        float p0 = __builtin_amdgcn_exp2f(s[cf][2 * h2]     - m_s);
        float p1 = __builtin_amdgcn_exp2f(s[cf][2 * h2 + 1] - m_s);
        unsigned u0 = __float_as_uint(p0) & 0xffff0000u;
        unsigned u1 = __float_as_uint(p1) & 0xffff0000u;
        rsum += __uint_as_float(u0) + __uint_as_float(u1);   // sum what we store
        pk[cf][h2] = (u0 >> 16) | u1;
      }
    rsum += __shfl_xor(rsum, 16);
    rsum += __shfl_xor(rsum, 32);
    l_s += rsum;

    // P tile write: 4 x ds_write_b64 (wave-private [i=cl][j])
    #pragma unroll
    for (int cf = 0; cf < 4; ++cf)
      *(uint2*)&pl[cl * PS + cf * 16 + 4 * g] = make_uint2(pk[cf][0], pk[cf][1]);

    // PV: A = P rows (b128), B = V^T rows
    bfrag ap[2];
    #pragma unroll
    for (int kk = 0; kk < 2; ++kk)
      ap[kk] = *(const bfrag*)&pl[cl * PS + kk * 32 + g8];
    __builtin_amdgcn_s_setprio(1);
    #pragma unroll
    for (int kk = 0; kk < 2; ++kk)
      #pragma unroll
      for (int df = 0; df < 4; ++df){
        bfrag bv = *(const bfrag*)&vc[(df * 16 + cl) * KS + kk * 32 + g8];
        o_acc[df] = __builtin_amdgcn_mfma_f32_16x16x32_bf16(ap[kk], bv, o_acc[df], 0, 0, 0);
      }
    __builtin_amdgcn_s_setprio(0);

    if (more){                                  // write prefetched tile, single barrier
      int nxt = cur ^ 1;
      #pragma unroll
      for (int r = 0; r < 2; ++r)
        *(uint4*)&k_lds[nxt][(r * 32 + krow) * KS + kcol] = ka[r];
      #pragma unroll
      for (int r = 0; r < 2; ++r){
        const u16* pv = (const u16*)&va[r];
        #pragma unroll
        for (int e2 = 0; e2 < 8; ++e2){
          int idx = (e2 + c8) & 7;
          v_lds[nxt][(kcol + idx) * KS + r * 32 + krow] = pv[idx];
        }
      }
      __syncthreads();
      cur = nxt;
    }
  }

  // epilogue: o_acc rows are i = 4g+reg, stats live at lane cl=i -> broadcast
  float inv = 1.0f / l_s;
  float invr[4];
  #pragma unroll
  for (int r = 0; r < 4; ++r) invr[r] = __shfl(inv, g * 20 + r);
  const int bb = bh >> 4, h = bh & 15;
  #pragma unroll
  for (int df = 0; df < 4; ++df)
    #pragma unroll
    for (int r = 0; r < 4; ++r){
      int row = i0 + w * 16 + 4 * g + r;
      int col = h * 64 + df * 16 + cl;
      aout[(size_t)(bb * 2048 + row) * 1024 + col] = f2bf(o_acc[df][r] * invr[r]);
    }
}

// ---------------- launch ----------------
extern "C" void kernel_launch(void* const* d_in, const int* in_sizes, int n_in,
                              void* d_out, int out_size, void* d_ws, size_t ws_size,
                              hipStream_t stream)
{
  const float* x     = (const float*)d_in[0];
  const float* w_in  = (const float*)d_in[1];
  const float* b_in  = (const float*)d_in[2];
  const float* w_out = (const float*)d_in[3];
  const float* b_out = (const float*)d_in[4];
  const int*   cmask = (const int*)d_in[5];

  u16* ws     = (u16*)d_ws;
  u16* xb     = ws;                 // 4096x1024
  u16* winb   = ws + 4194304;       // 3072x1024
  u16* woutb  = ws + 7340032;       // 1024x1024
  u16* qs     = ws + 8388608;       // q,k,v: 3 x [2,16,2048,64]
  u16* attn_o = ws + 20971520;      // 4096x1024

  cvt_kernel<<<4096, 256, 0, stream>>>(x, xb, 4194304);
  cvt_kernel<<<3072, 256, 0, stream>>>(w_in, winb, 3145728);
  cvt_kernel<<<1024, 256, 0, stream>>>(w_out, woutb, 1048576);

  gemm_bt<1><<<dim3(24, 32), 256, 0, stream>>>(xb, winb, b_in, nullptr, qs, 4096, 3072, 1024);

  attn_kernel<<<dim3(32, 32), 256, 0, stream>>>(qs, qs + 4194304, qs + 8388608, attn_o, cmask);

  gemm_bt<0><<<dim3(8, 32), 256, 0, stream>>>(attn_o, woutb, b_out, (float*)d_out, nullptr,
                                              4096, 1024, 1024);
}